// Round 1
// 2718.337 us; speedup vs baseline: 1.9260x; 1.9260x over previous
//
#include <hip/hip_runtime.h>
#include <hip/hip_bf16.h>

typedef unsigned short u16;
typedef short bf16x8 __attribute__((ext_vector_type(8)));
typedef float f32x4 __attribute__((ext_vector_type(4)));

#define BB 2
#define SS 2048
#define DD 2048
#define HH 16
#define HDIM 128
#define HIDF 5632
#define MROWS (BB*SS)   // 4096

__device__ __forceinline__ float bf2f(u16 x){
  union { unsigned u; float f; } c; c.u = ((unsigned)x) << 16; return c.f;
}
__device__ __forceinline__ u16 f2bf(float f){
  union { float f; unsigned u; } c; c.f = f;
  unsigned u = c.u;
  u += 0x7FFFu + ((u >> 16) & 1u);   // RNE
  return (u16)(u >> 16);
}
__device__ __forceinline__ float clamp_sig(float v){
  // NaN -> +8192 (diagnostic signal); legit values never reach +-8192
  return fmaxf(fminf(v, 8192.f), -8192.f);
}

// Per-block input-dtype detection: scan 2048 u16 of a weight tensor.
// bf16 weights (sigma=0.02): exponent field always < 0x90.
// fp32 data read as u16: even halves are mantissa garbage, ~44% >= 0x90.
__device__ int detect_fp32(const u16* __restrict__ probe){
  __shared__ int sflag;
  if (threadIdx.x == 0) sflag = 0;
  __syncthreads();
  int bad = 0;
  #pragma unroll
  for (int i = 0; i < 8; i++){
    u16 v = probe[threadIdx.x * 8 + i];
    int e = (v >> 7) & 0xFF;
    bad += (e >= 0x90);
  }
  if (bad) atomicAdd(&sflag, bad);
  __syncthreads();
  return sflag > 16;
}

// ---------------- RMSNorm: row of 2048 -> bf16 out ----------------
__global__ __launch_bounds__(256) void rmsnorm_k(const void* __restrict__ src,
                                                 const void* __restrict__ w,
                                                 u16* __restrict__ y,
                                                 const u16* __restrict__ probe,
                                                 int src_probe){
  int f = detect_fp32(probe);
  int sdt = src_probe ? f : 0;
  int row = blockIdx.x, t = threadIdx.x;
  float v[8];
  if (sdt){
    const float* xr = (const float*)src + (size_t)row * DD + t * 8;
    #pragma unroll
    for (int i = 0; i < 8; i++) v[i] = xr[i];
  } else {
    const u16* xr = (const u16*)src + (size_t)row * DD + t * 8;
    uint4 pk = *(const uint4*)xr;
    u16* pv = (u16*)&pk;
    #pragma unroll
    for (int i = 0; i < 8; i++) v[i] = bf2f(pv[i]);
  }
  float ss = 0.f;
  #pragma unroll
  for (int i = 0; i < 8; i++) ss += v[i] * v[i];
  #pragma unroll
  for (int off = 32; off > 0; off >>= 1) ss += __shfl_down(ss, off, 64);
  __shared__ float red[4];
  if ((t & 63) == 0) red[t >> 6] = ss;
  __syncthreads();
  if (t == 0){
    float s = red[0] + red[1] + red[2] + red[3];
    red[0] = rsqrtf(s / (float)DD + 1e-5f);
  }
  __syncthreads();
  float r = red[0];
  float wf[8];
  if (f){
    const float* wp = (const float*)w + t * 8;
    #pragma unroll
    for (int i = 0; i < 8; i++) wf[i] = wp[i];
  } else {
    const u16* wp = (const u16*)w + t * 8;
    uint4 wk = *(const uint4*)wp;
    u16* pw = (u16*)&wk;
    #pragma unroll
    for (int i = 0; i < 8; i++) wf[i] = bf2f(pw[i]);
  }
  u16 ob[8];
  #pragma unroll
  for (int i = 0; i < 8; i++){
    float yn = v[i] * r;
    if (!f) yn = bf2f(f2bf(yn));   // bf16 world: ref casts to bf16 before *w
    ob[i] = f2bf(yn * wf[i]);
  }
  *(uint4*)(y + (size_t)row * DD + t * 8) = *(uint4*)ob;
}

// ---------------- RoPE in-place on [B,S,H,HD] (ws, bf16) ----------------
__global__ __launch_bounds__(256) void rope_k(u16* __restrict__ x,
                                              const void* __restrict__ cosb,
                                              const void* __restrict__ sinb,
                                              const u16* __restrict__ probe){
  int f = detect_fp32(probe);
  size_t i = (size_t)blockIdx.x * 256 + threadIdx.x;  // pair index
  int p = (int)(i & 63);
  int s = (int)((i >> 10) & (SS - 1));
  u16* px = x + i * 2;
  float a = bf2f(px[0]), b = bf2f(px[1]);
  float c, sn;
  if (f){
    c  = ((const float*)cosb)[s * 64 + p];
    sn = ((const float*)sinb)[s * 64 + p];
  } else {
    c  = bf2f(((const u16*)cosb)[s * 64 + p]);
    sn = bf2f(((const u16*)sinb)[s * 64 + p]);
  }
  px[0] = f2bf(a * c - b * sn);
  px[1] = f2bf(a * sn + b * c);
}

// ---- B staging helper: stage B[k0..k0+32][n0..n0+128] (row-major [K][N])
// into Bs[n][k] (128 rows x 32 u16). Dual dtype. ----
__device__ __forceinline__ void stage_B(const void* __restrict__ B, u16* Bs,
                                        int k0, int n0, int N, int f, int t){
  if (!f){
    const u16* Bh = (const u16*)B;
    #pragma unroll
    for (int i = 0; i < 2; i++){
      int c = t + 256 * i;
      int kr = c >> 4, cg = c & 15;
      uint4 pk = *(const uint4*)(Bh + (size_t)(k0 + kr) * N + n0 + cg * 8);
      u16* tv = (u16*)&pk;
      #pragma unroll
      for (int j = 0; j < 8; j++) Bs[(cg * 8 + j) * 32 + kr] = tv[j];
    }
  } else {
    const float* Bf = (const float*)B;
    #pragma unroll
    for (int i = 0; i < 2; i++){
      int c = t + 256 * i;
      int kr = c >> 4, cg = c & 15;
      const float* gp = Bf + (size_t)(k0 + kr) * N + n0 + cg * 8;
      float4 x0 = *(const float4*)gp;
      float4 x1 = *(const float4*)(gp + 4);
      u16* d = Bs + (cg * 8) * 32 + kr;
      d[0*32] = f2bf(x0.x); d[1*32] = f2bf(x0.y);
      d[2*32] = f2bf(x0.z); d[3*32] = f2bf(x0.w);
      d[4*32] = f2bf(x1.x); d[5*32] = f2bf(x1.y);
      d[6*32] = f2bf(x1.z); d[7*32] = f2bf(x1.w);
    }
  }
}

// ---------------- MFMA GEMM: C[M,N] = A[M,K] @ B[K,N] (+Res) ----------------
// A: bf16 ws. B: d_in weight, row-major [K][N], dual-dtype.
// out_probe: if set and inputs are fp32, C is written as fp32 (d_out case).
template<int EPI>
__global__ __launch_bounds__(256) void gemm_bn(const u16* __restrict__ A,
                                               const void* __restrict__ B,
                                               void* __restrict__ C,
                                               const void* __restrict__ Res,
                                               const u16* __restrict__ probe,
                                               int M, int N, int K,
                                               int res_probe, int out_probe){
  int f = detect_fp32(probe);
  __shared__ u16 As[128 * 32];
  __shared__ u16 Bs[128 * 32];
  int t = threadIdx.x;
  int l = t & 63, w = t >> 6;
  int wm = w >> 1, wn = w & 1;
  int m0 = blockIdx.y * 128, n0 = blockIdx.x * 128;
  const int lrow = l & 15, lq = l >> 4;

  f32x4 acc[4][4];
  #pragma unroll
  for (int i = 0; i < 4; i++)
    #pragma unroll
    for (int j = 0; j < 4; j++) acc[i][j] = (f32x4){0.f, 0.f, 0.f, 0.f};

  for (int k0 = 0; k0 < K; k0 += 32){
    #pragma unroll
    for (int i = 0; i < 2; i++){
      int c = t + 256 * i;
      int row = c >> 2, kp = (c & 3) * 8;
      *(uint4*)(As + (size_t)c * 8) =
          *(const uint4*)(A + (size_t)(m0 + row) * K + k0 + kp);
    }
    stage_B(B, Bs, k0, n0, N, f, t);
    __syncthreads();
    bf16x8 aF[4], bF[4];
    #pragma unroll
    for (int mi = 0; mi < 4; mi++)
      aF[mi] = *(const bf16x8*)(As + (wm * 64 + mi * 16 + lrow) * 32 + lq * 8);
    #pragma unroll
    for (int ni = 0; ni < 4; ni++)
      bF[ni] = *(const bf16x8*)(Bs + (wn * 64 + ni * 16 + lrow) * 32 + lq * 8);
    #pragma unroll
    for (int mi = 0; mi < 4; mi++)
      #pragma unroll
      for (int ni = 0; ni < 4; ni++)
        acc[mi][ni] = __builtin_amdgcn_mfma_f32_16x16x32_bf16(aF[mi], bF[ni], acc[mi][ni], 0, 0, 0);
    __syncthreads();
  }

  int rdt = res_probe ? f : 0;
  int odt = out_probe ? f : 0;
  #pragma unroll
  for (int mi = 0; mi < 4; mi++){
    #pragma unroll
    for (int ni = 0; ni < 4; ni++){
      #pragma unroll
      for (int r = 0; r < 4; r++){
        int row = m0 + wm * 64 + mi * 16 + lq * 4 + r;
        int col = n0 + wn * 64 + ni * 16 + lrow;
        float v = acc[mi][ni][r];
        if (EPI == 1){
          if (rdt) v += ((const float*)Res)[(size_t)row * N + col];
          else     v += bf2f(((const u16*)Res)[(size_t)row * N + col]);
        }
        v = clamp_sig(v);
        if (odt) ((float*)C)[(size_t)row * N + col] = v;
        else     ((u16*)C)[(size_t)row * N + col] = f2bf(v);
      }
    }
  }
}

// ---------------- Dual-B MFMA GEMM with SwiGLU epilogue ----------------
__global__ __launch_bounds__(256) void gemm_ffn(const u16* __restrict__ A,
                                                const void* __restrict__ B1,
                                                const void* __restrict__ B3,
                                                u16* __restrict__ G,
                                                const u16* __restrict__ probe,
                                                int M, int N, int K){
  int f = detect_fp32(probe);
  __shared__ u16 As[128 * 32];
  __shared__ u16 B1s[128 * 32];
  __shared__ u16 B3s[128 * 32];
  int t = threadIdx.x;
  int l = t & 63, w = t >> 6;
  int wm = w >> 1, wn = w & 1;
  int m0 = blockIdx.y * 128, n0 = blockIdx.x * 128;
  const int lrow = l & 15, lq = l >> 4;

  f32x4 acc1[4][4], acc3[4][4];
  #pragma unroll
  for (int i = 0; i < 4; i++)
    #pragma unroll
    for (int j = 0; j < 4; j++){
      acc1[i][j] = (f32x4){0.f, 0.f, 0.f, 0.f};
      acc3[i][j] = (f32x4){0.f, 0.f, 0.f, 0.f};
    }

  for (int k0 = 0; k0 < K; k0 += 32){
    #pragma unroll
    for (int i = 0; i < 2; i++){
      int c = t + 256 * i;
      int row = c >> 2, kp = (c & 3) * 8;
      *(uint4*)(As + (size_t)c * 8) =
          *(const uint4*)(A + (size_t)(m0 + row) * K + k0 + kp);
    }
    stage_B(B1, B1s, k0, n0, N, f, t);
    stage_B(B3, B3s, k0, n0, N, f, t);
    __syncthreads();
    bf16x8 aF[4], b1F[4], b3F[4];
    #pragma unroll
    for (int mi = 0; mi < 4; mi++)
      aF[mi] = *(const bf16x8*)(As + (wm * 64 + mi * 16 + lrow) * 32 + lq * 8);
    #pragma unroll
    for (int ni = 0; ni < 4; ni++){
      b1F[ni] = *(const bf16x8*)(B1s + (wn * 64 + ni * 16 + lrow) * 32 + lq * 8);
      b3F[ni] = *(const bf16x8*)(B3s + (wn * 64 + ni * 16 + lrow) * 32 + lq * 8);
    }
    #pragma unroll
    for (int mi = 0; mi < 4; mi++)
      #pragma unroll
      for (int ni = 0; ni < 4; ni++){
        acc1[mi][ni] = __builtin_amdgcn_mfma_f32_16x16x32_bf16(aF[mi], b1F[ni], acc1[mi][ni], 0, 0, 0);
        acc3[mi][ni] = __builtin_amdgcn_mfma_f32_16x16x32_bf16(aF[mi], b3F[ni], acc3[mi][ni], 0, 0, 0);
      }
    __syncthreads();
  }

  #pragma unroll
  for (int mi = 0; mi < 4; mi++){
    #pragma unroll
    for (int ni = 0; ni < 4; ni++){
      #pragma unroll
      for (int r = 0; r < 4; r++){
        int row = m0 + wm * 64 + mi * 16 + lq * 4 + r;
        int col = n0 + wn * 64 + ni * 16 + lrow;
        float g1 = acc1[mi][ni][r];
        float g3 = acc3[mi][ni][r];
        if (!f){ g1 = bf2f(f2bf(g1)); g3 = bf2f(f2bf(g3)); }
        float s  = g1 / (1.f + __expf(-g1));
        if (!f) s = bf2f(f2bf(s));
        float pr = s * g3;
        G[(size_t)row * N + col] = f2bf(clamp_sig(pr));
      }
    }
  }
}

// ---------------- MFMA flash attention ----------------
// Grid: 1024 blocks = B(2) * H(16) * (S/64=32 q-tiles), 256 threads (4 waves).
// Each wave owns 16 q-rows. K-tile = 64 keys.
//  - QK^T computed SWAPPED: mfma(K_frag, Q_frag) -> S^T[k][q], so each lane's
//    4 values (C rows) are k-consecutive -> P packs to LDS with b64 writes.
//  - K LDS: [64][128] bf16, XOR swizzle byte ^= (row&7)<<4 (bank-conflict fix).
//  - V LDS: transposed oct-planes Voct[k>>3][d][k&7] via in-register dword
//    transpose; swizzle byte ^= ((d>>1)&7)<<4 (write d=2*lane and read d=16n+q
//    both at the b128 bank floor; bijective).
//  - Online softmax fully wave-parallel (reg-max + shfl_xor over 4 lane-groups).
__global__ __launch_bounds__(256) void attn_k(const u16* __restrict__ Qg,
                                              const u16* __restrict__ Kg,
                                              const u16* __restrict__ Vg,
                                              u16* __restrict__ Og){
  __shared__ __align__(16) char KsB[64 * 256];     // 16 KB: K[64][128] bf16 (swizzled)
  __shared__ __align__(16) char VoB[8 * 2048];     // 16 KB: Voct[8][128][8] bf16 (swizzled)
  __shared__ __align__(16) u16  Ps[4][16 * 72];    // 9 KB:  per-wave P[16 q][64 k], stride 72

  const int t  = threadIdx.x;
  const int ln = t & 63;
  const int w  = t >> 6;
  const int q  = ln & 15;     // q-sub-row (fragment row/col index)
  const int g  = ln >> 4;     // lane group 0..3 (k-slice index)

  // XCD-aware swizzle: 1024 blocks, 8 XCDs -> 128-block contiguous chunks.
  int bid = (int)(blockIdx.x);
  int swz = (bid & 7) * 128 + (bid >> 3);
  int qt = swz & 31;
  int h  = (swz >> 5) & 15;
  int b  = swz >> 9;

  const size_t bbase = ((size_t)b * SS) * DD + (size_t)h * HDIM;
  const int q0 = qt * 64;
  const float scale = 0.08838834764831845f;  // 1/sqrt(128)

  u16* Psw = &Ps[w][0];

  // ---- Q fragments (pre-scaled bf16), held all kernel: Q[q0+w*16+q][d] ----
  bf16x8 qF[4];
  {
    const u16* qp = Qg + bbase + (size_t)(q0 + w * 16 + q) * DD + g * 8;
    #pragma unroll
    for (int ds = 0; ds < 4; ds++){
      uint4 raw = *(const uint4*)(qp + ds * 32);
      u16* rw = (u16*)&raw;
      u16 sc8[8];
      #pragma unroll
      for (int j = 0; j < 8; j++) sc8[j] = f2bf(bf2f(rw[j]) * scale);
      qF[ds] = *(bf16x8*)sc8;
    }
  }

  f32x4 ov[8];
  #pragma unroll
  for (int n = 0; n < 8; n++) ov[n] = (f32x4){0.f, 0.f, 0.f, 0.f};
  float m_state = -1e30f;
  float l_state = 0.f;

  for (int kt = 0; kt < 32; kt++){
    const int k0 = kt * 64;
    __syncthreads();   // previous iteration's LDS reads complete

    // ---- stage K tile: all 256 threads, b128 swizzled writes ----
    #pragma unroll
    for (int i = 0; i < 4; i++){
      int c = t + 256 * i;
      int row = c >> 4, cb = c & 15;
      uint4 val = *(const uint4*)(Kg + bbase + (size_t)(k0 + row) * DD + cb * 8);
      *(uint4*)(KsB + (((row << 8) | (cb << 4)) ^ ((row & 7) << 4))) = val;
    }
    // ---- stage V tile transposed: wave w handles oct planes 2w, 2w+1 ----
    #pragma unroll
    for (int oo = 0; oo < 2; oo++){
      int oct = w * 2 + oo;
      unsigned r[8];
      #pragma unroll
      for (int kk = 0; kk < 8; kk++)
        r[kk] = *(const unsigned*)(Vg + bbase + (size_t)(k0 + oct * 8 + kk) * DD + 2 * ln);
      uint4 lo, hi;
      lo.x = (r[0] & 0xffffu) | (r[1] << 16);
      lo.y = (r[2] & 0xffffu) | (r[3] << 16);
      lo.z = (r[4] & 0xffffu) | (r[5] << 16);
      lo.w = (r[6] & 0xffffu) | (r[7] << 16);
      hi.x = (r[0] >> 16) | (r[1] & 0xffff0000u);
      hi.y = (r[2] >> 16) | (r[3] & 0xffff0000u);
      hi.z = (r[4] >> 16) | (r[5] & 0xffff0000u);
      hi.w = (r[6] >> 16) | (r[7] & 0xffff0000u);
      int a0 = oct * 2048 + ((ln * 32) ^ ((ln & 7) << 4));   // d = 2*ln
      *(uint4*)(VoB + a0) = lo;                              // d even
      *(uint4*)(VoB + (a0 ^ 16)) = hi;                       // d = 2*ln+1
    }
    __syncthreads();   // staging visible

    // ---- QK^T (swapped): sc4[m] = S^T[k-subtile m][q], lane holds
    //      k = k0 + m*16 + g*4 + r  (r = reg), col q = ln&15 ----
    f32x4 sc4[4];
    #pragma unroll
    for (int m = 0; m < 4; m++) sc4[m] = (f32x4){0.f, 0.f, 0.f, 0.f};
    #pragma unroll
    for (int m = 0; m < 4; m++){
      int row = m * 16 + q;
      #pragma unroll
      for (int ds = 0; ds < 4; ds++){
        bf16x8 kf = *(const bf16x8*)(KsB +
            (((row << 8) | (ds << 6) | (g << 4)) ^ ((row & 7) << 4)));
        sc4[m] = __builtin_amdgcn_mfma_f32_16x16x32_bf16(kf, qF[ds], sc4[m], 0, 0, 0);
      }
    }

    // ---- online softmax (wave-parallel; rows are q = ln&15) ----
    float mt = -1e30f;
    #pragma unroll
    for (int m = 0; m < 4; m++){
      mt = fmaxf(mt, fmaxf(fmaxf(sc4[m][0], sc4[m][1]), fmaxf(sc4[m][2], sc4[m][3])));
    }
    mt = fmaxf(mt, __shfl_xor(mt, 16));
    mt = fmaxf(mt, __shfl_xor(mt, 32));
    float m_new = fmaxf(m_state, mt);
    float alpha = __expf(m_state - m_new);
    float rs = 0.f;
    #pragma unroll
    for (int m = 0; m < 4; m++){
      float p0 = __expf(sc4[m][0] - m_new);
      float p1 = __expf(sc4[m][1] - m_new);
      float p2 = __expf(sc4[m][2] - m_new);
      float p3 = __expf(sc4[m][3] - m_new);
      rs += (p0 + p1) + (p2 + p3);
      uint2 pw;
      pw.x = (unsigned)f2bf(p0) | ((unsigned)f2bf(p1) << 16);
      pw.y = (unsigned)f2bf(p2) | ((unsigned)f2bf(p3) << 16);
      // Ps[q][k], k = m*16 + g*4 .. +4  (stride 72 u16; 8B aligned)
      *(uint2*)(Psw + q * 72 + m * 16 + g * 4) = pw;
    }
    rs += __shfl_xor(rs, 16);
    rs += __shfl_xor(rs, 32);
    l_state = l_state * alpha + rs;
    m_state = m_new;

    // ---- rescale O accumulators: component r is q-row g*4+r ----
    float a0 = __shfl(alpha, g * 4 + 0);
    float a1 = __shfl(alpha, g * 4 + 1);
    float a2 = __shfl(alpha, g * 4 + 2);
    float a3 = __shfl(alpha, g * 4 + 3);
    #pragma unroll
    for (int n = 0; n < 8; n++){
      ov[n][0] *= a0; ov[n][1] *= a1; ov[n][2] *= a2; ov[n][3] *= a3;
    }

    // ---- PV: O[q][d] += P[q][k] * V[k][d] (per-wave Ps, no barrier) ----
    bf16x8 pA0 = *(const bf16x8*)(Psw + q * 72 + g * 8);
    bf16x8 pA1 = *(const bf16x8*)(Psw + q * 72 + 32 + g * 8);
    #pragma unroll
    for (int n = 0; n < 8; n++){
      int d = n * 16 + q;
      int sw = ((d >> 1) & 7) << 4;
      bf16x8 v0 = *(const bf16x8*)(VoB + g * 2048 + ((d << 4) ^ sw));
      bf16x8 v1 = *(const bf16x8*)(VoB + (4 + g) * 2048 + ((d << 4) ^ sw));
      ov[n] = __builtin_amdgcn_mfma_f32_16x16x32_bf16(pA0, v0, ov[n], 0, 0, 0);
      ov[n] = __builtin_amdgcn_mfma_f32_16x16x32_bf16(pA1, v1, ov[n], 0, 0, 0);
    }
  }

  // ---- epilogue: O / l, write bf16 ----
  float li = 1.f / fmaxf(l_state, 1e-30f);   // valid for q = ln&15
  float l0 = __shfl(li, g * 4 + 0);
  float l1 = __shfl(li, g * 4 + 1);
  float l2 = __shfl(li, g * 4 + 2);
  float l3 = __shfl(li, g * 4 + 3);
  #pragma unroll
  for (int n = 0; n < 8; n++){
    int srow = q0 + w * 16 + g * 4;
    int d = n * 16 + q;
    u16* po = Og + bbase + (size_t)srow * DD + d;
    po[0]        = f2bf(clamp_sig(ov[n][0] * l0));
    po[DD]       = f2bf(clamp_sig(ov[n][1] * l1));
    po[2 * DD]   = f2bf(clamp_sig(ov[n][2] * l2));
    po[3 * DD]   = f2bf(clamp_sig(ov[n][3] * l3));
  }
}

extern "C" void kernel_launch(void* const* d_in, const int* in_sizes, int n_in,
                              void* d_out, int out_size, void* d_ws, size_t ws_size,
                              hipStream_t stream){
  (void)in_sizes; (void)n_in; (void)out_size; (void)ws_size;
  const void* x   = d_in[0];
  const void* fc  = d_in[1];
  const void* fs  = d_in[2];
  const void* wq  = d_in[3];
  const void* wk  = d_in[4];
  const void* wv  = d_in[5];
  const void* wo  = d_in[6];
  const void* w1  = d_in[7];
  const void* w2  = d_in[8];
  const void* w3  = d_in[9];
  const void* anw = d_in[10];
  const void* fnw = d_in[11];
  const u16* probe = (const u16*)wq;   // dtype probe tensor
  void* out = d_out;

  // ---- workspace layout (total ~84 MB) ----
  char* ws = (char*)d_ws;
  size_t off = 0;
  auto alloc = [&](size_t bytes) -> u16* {
    u16* p = (u16*)(ws + off);
    off += (bytes + 255) & ~(size_t)255;
    return p;
  };
  const size_t SZ_MD = (size_t)MROWS * DD * 2;      // 16.78 MB

  u16* XN  = alloc(SZ_MD);
  u16* Qb  = alloc(SZ_MD);
  u16* Kb  = alloc(SZ_MD);
  u16* Vb  = alloc(SZ_MD);
  u16* Hb  = alloc(SZ_MD);
  u16* AO  = XN;                 // alias: XN dead when attention output written
  u16* G   = Qb;                 // alias: Q/K/V dead in FFN phase (46.1 <= 50.3 MB)

  // --- attention sub-block ---
  rmsnorm_k<<<MROWS, 256, 0, stream>>>(x, anw, XN, probe, 1);
  gemm_bn<0><<<dim3(16, 32), 256, 0, stream>>>(XN, wq, Qb, nullptr, probe, MROWS, DD, DD, 0, 0);
  gemm_bn<0><<<dim3(16, 32), 256, 0, stream>>>(XN, wk, Kb, nullptr, probe, MROWS, DD, DD, 0, 0);
  gemm_bn<0><<<dim3(16, 32), 256, 0, stream>>>(XN, wv, Vb, nullptr, probe, MROWS, DD, DD, 0, 0);
  rope_k<<<16384, 256, 0, stream>>>(Qb, fc, fs, probe);
  rope_k<<<16384, 256, 0, stream>>>(Kb, fc, fs, probe);
  attn_k<<<1024, 256, 0, stream>>>(Qb, Kb, Vb, AO);
  gemm_bn<1><<<dim3(16, 32), 256, 0, stream>>>(AO, wo, Hb, x, probe, MROWS, DD, DD, 1, 0);

  // --- SwiGLU FFN sub-block ---
  rmsnorm_k<<<MROWS, 256, 0, stream>>>(Hb, fnw, XN, probe, 0);
  gemm_ffn<<<dim3(44, 32), 256, 0, stream>>>(XN, w1, w3, G, probe, MROWS, HIDF, DD);
  gemm_bn<1><<<dim3(16, 32), 256, 0, stream>>>(G, w2, out, Hb, probe, MROWS, DD, HIDF, 0, 1);
}

// Round 2
// 1480.814 us; speedup vs baseline: 3.5357x; 1.8357x over previous
//
#include <hip/hip_runtime.h>
#include <hip/hip_bf16.h>

typedef unsigned short u16;
typedef short bf16x8 __attribute__((ext_vector_type(8)));
typedef float f32x4 __attribute__((ext_vector_type(4)));

#define BB 2
#define SS 2048
#define DD 2048
#define HH 16
#define HDIM 128
#define HIDF 5632
#define MROWS (BB*SS)   // 4096

__device__ __forceinline__ float bf2f(u16 x){
  union { unsigned u; float f; } c; c.u = ((unsigned)x) << 16; return c.f;
}
__device__ __forceinline__ u16 f2bf(float f){
  union { float f; unsigned u; } c; c.f = f;
  unsigned u = c.u;
  u += 0x7FFFu + ((u >> 16) & 1u);   // RNE
  return (u16)(u >> 16);
}
__device__ __forceinline__ float clamp_sig(float v){
  // NaN -> +8192 (diagnostic signal); legit values never reach +-8192
  return fmaxf(fminf(v, 8192.f), -8192.f);
}

// async global->LDS, 16B per lane. lds base must be wave-uniform.
__device__ __forceinline__ void gload16(const void* g, void* l){
  __builtin_amdgcn_global_load_lds((const __attribute__((address_space(1))) void*)g,
                                   (__attribute__((address_space(3))) void*)l,
                                   16, 0, 0);
}

// Per-block input-dtype detection: scan 2048 u16 of a weight tensor.
// bf16 weights (sigma=0.02): exponent field always < 0x90.
// fp32 data read as u16: even halves are mantissa garbage, ~44% >= 0x90.
__device__ int detect_fp32(const u16* __restrict__ probe){
  __shared__ int sflag;
  if (threadIdx.x == 0) sflag = 0;
  __syncthreads();
  int bad = 0;
  #pragma unroll
  for (int i = 0; i < 8; i++){
    u16 v = probe[threadIdx.x * 8 + i];
    int e = (v >> 7) & 0xFF;
    bad += (e >= 0x90);
  }
  if (bad) atomicAdd(&sflag, bad);
  __syncthreads();
  return sflag > 16;
}

// ---------------- weight transpose+cast: W[K][N] (f?fp32:bf16) -> WT[N][K] bf16 ----
// grid: (N/64, K/64), 256 threads. 64x64 tile via LDS.
__global__ __launch_bounds__(256) void transpose_k(const void* __restrict__ W,
                                                   u16* __restrict__ WT,
                                                   int K, int N,
                                                   const u16* __restrict__ probe){
  int f = detect_fp32(probe);
  __shared__ u16 T[64][72];   // +8 pad; rows 144B (16B-aligned)
  int n0 = blockIdx.x * 64, k0 = blockIdx.y * 64;
  int t = threadIdx.x;
  int row = t >> 3, c8 = (t & 7) * 8;
  #pragma unroll
  for (int i = 0; i < 2; i++){
    int r = row + 32 * i;
    if (!f){
      uint4 v = *(const uint4*)((const u16*)W + (size_t)(k0 + r) * N + n0 + c8);
      *(uint4*)&T[r][c8] = v;
    } else {
      const float* gp = (const float*)W + (size_t)(k0 + r) * N + n0 + c8;
      float4 a = *(const float4*)gp;
      float4 b = *(const float4*)(gp + 4);
      u16 tmp[8] = {f2bf(a.x), f2bf(a.y), f2bf(a.z), f2bf(a.w),
                    f2bf(b.x), f2bf(b.y), f2bf(b.z), f2bf(b.w)};
      *(uint4*)&T[r][c8] = *(uint4*)tmp;
    }
  }
  __syncthreads();
  #pragma unroll
  for (int i = 0; i < 2; i++){
    int r = row + 32 * i;      // output n-offset
    u16 o[8];
    #pragma unroll
    for (int j = 0; j < 8; j++) o[j] = T[c8 + j][r];
    *(uint4*)(WT + (size_t)(n0 + r) * K + k0 + c8) = *(uint4*)o;
  }
}

// ---------------- RMSNorm: row of 2048 -> bf16 out ----------------
__global__ __launch_bounds__(256) void rmsnorm_k(const void* __restrict__ src,
                                                 const void* __restrict__ w,
                                                 u16* __restrict__ y,
                                                 const u16* __restrict__ probe,
                                                 int src_probe){
  int f = detect_fp32(probe);
  int sdt = src_probe ? f : 0;
  int row = blockIdx.x, t = threadIdx.x;
  float v[8];
  if (sdt){
    const float* xr = (const float*)src + (size_t)row * DD + t * 8;
    float4 p0 = *(const float4*)xr;
    float4 p1 = *(const float4*)(xr + 4);
    v[0] = p0.x; v[1] = p0.y; v[2] = p0.z; v[3] = p0.w;
    v[4] = p1.x; v[5] = p1.y; v[6] = p1.z; v[7] = p1.w;
  } else {
    const u16* xr = (const u16*)src + (size_t)row * DD + t * 8;
    uint4 pk = *(const uint4*)xr;
    u16* pv = (u16*)&pk;
    #pragma unroll
    for (int i = 0; i < 8; i++) v[i] = bf2f(pv[i]);
  }
  float ss = 0.f;
  #pragma unroll
  for (int i = 0; i < 8; i++) ss += v[i] * v[i];
  #pragma unroll
  for (int off = 32; off > 0; off >>= 1) ss += __shfl_down(ss, off, 64);
  __shared__ float red[4];
  if ((t & 63) == 0) red[t >> 6] = ss;
  __syncthreads();
  if (t == 0){
    float s = red[0] + red[1] + red[2] + red[3];
    red[0] = rsqrtf(s / (float)DD + 1e-5f);
  }
  __syncthreads();
  float r = red[0];
  float wf[8];
  if (f){
    const float* wp = (const float*)w + t * 8;
    float4 a = *(const float4*)wp;
    float4 b = *(const float4*)(wp + 4);
    wf[0] = a.x; wf[1] = a.y; wf[2] = a.z; wf[3] = a.w;
    wf[4] = b.x; wf[5] = b.y; wf[6] = b.z; wf[7] = b.w;
  } else {
    const u16* wp = (const u16*)w + t * 8;
    uint4 wk = *(const uint4*)wp;
    u16* pw = (u16*)&wk;
    #pragma unroll
    for (int i = 0; i < 8; i++) wf[i] = bf2f(pw[i]);
  }
  u16 ob[8];
  #pragma unroll
  for (int i = 0; i < 8; i++){
    float yn = v[i] * r;
    if (!f) yn = bf2f(f2bf(yn));   // bf16 world: ref casts to bf16 before *w
    ob[i] = f2bf(yn * wf[i]);
  }
  *(uint4*)(y + (size_t)row * DD + t * 8) = *(uint4*)ob;
}

// ---------------- RoPE in-place on [B,S,H,HD] (ws, bf16) ----------------
__global__ __launch_bounds__(256) void rope_k(u16* __restrict__ x,
                                              const void* __restrict__ cosb,
                                              const void* __restrict__ sinb,
                                              const u16* __restrict__ probe){
  int f = detect_fp32(probe);
  size_t i = (size_t)blockIdx.x * 256 + threadIdx.x;  // pair index
  int p = (int)(i & 63);
  int s = (int)((i >> 10) & (SS - 1));
  u16* px = x + i * 2;
  float a = bf2f(px[0]), b = bf2f(px[1]);
  float c, sn;
  if (f){
    c  = ((const float*)cosb)[s * 64 + p];
    sn = ((const float*)sinb)[s * 64 + p];
  } else {
    c  = bf2f(((const u16*)cosb)[s * 64 + p]);
    sn = bf2f(((const u16*)sinb)[s * 64 + p]);
  }
  px[0] = f2bf(a * c - b * sn);
  px[1] = f2bf(a * sn + b * c);
}

// ---------------- MFMA GEMM (m97 structure): C[M,N] = A[M,K] @ BT[N,K]^T (+Res) ----
// A, BT: bf16, k-contiguous. global_load_lds width-16 staging, linear LDS,
// 128x128 tile, BK=32, XCD-aware block swizzle (grid % 8 == 0).
template<int EPI>
__global__ __launch_bounds__(256) void gemm_bt(const u16* __restrict__ A,
                                               const u16* __restrict__ BT,
                                               void* __restrict__ C,
                                               const void* __restrict__ Res,
                                               const u16* __restrict__ probe,
                                               int M, int N, int K,
                                               int res_probe, int out_probe){
  int f = detect_fp32(probe);
  __shared__ u16 As[128 * 32];
  __shared__ u16 Bs[128 * 32];
  int t = threadIdx.x;
  int l = t & 63, w = t >> 6;
  int wm = w >> 1, wn = w & 1;
  int gx = gridDim.x, nwg = gx * gridDim.y;
  int orig = blockIdx.x + gx * blockIdx.y;
  int wg = (orig & 7) * (nwg >> 3) + (orig >> 3);
  int m0 = (wg / gx) * 128, n0 = (wg % gx) * 128;
  const int lrow = l & 15, lq = l >> 4;

  f32x4 acc[4][4];
  #pragma unroll
  for (int i = 0; i < 4; i++)
    #pragma unroll
    for (int j = 0; j < 4; j++) acc[i][j] = (f32x4){0.f, 0.f, 0.f, 0.f};

  const u16* gA[2]; const u16* gB[2];
  #pragma unroll
  for (int i = 0; i < 2; i++){
    int c = i * 256 + t;
    gA[i] = A  + (size_t)(m0 + (c >> 2)) * K + (c & 3) * 8;
    gB[i] = BT + (size_t)(n0 + (c >> 2)) * K + (c & 3) * 8;
  }
  u16* lA = As + (size_t)w * 512;   // wave-uniform LDS bases (u16 units)
  u16* lB = Bs + (size_t)w * 512;

  for (int k0 = 0; k0 < K; k0 += 32){
    #pragma unroll
    for (int i = 0; i < 2; i++){
      gload16(gA[i] + k0, lA + i * 2048);
      gload16(gB[i] + k0, lB + i * 2048);
    }
    __syncthreads();
    bf16x8 aF[4], bF[4];
    #pragma unroll
    for (int mi = 0; mi < 4; mi++)
      aF[mi] = *(const bf16x8*)(As + (wm * 64 + mi * 16 + lrow) * 32 + lq * 8);
    #pragma unroll
    for (int ni = 0; ni < 4; ni++)
      bF[ni] = *(const bf16x8*)(Bs + (wn * 64 + ni * 16 + lrow) * 32 + lq * 8);
    #pragma unroll
    for (int mi = 0; mi < 4; mi++)
      #pragma unroll
      for (int ni = 0; ni < 4; ni++)
        acc[mi][ni] = __builtin_amdgcn_mfma_f32_16x16x32_bf16(aF[mi], bF[ni], acc[mi][ni], 0, 0, 0);
    __syncthreads();
  }

  int rdt = res_probe ? f : 0;
  int odt = out_probe ? f : 0;
  #pragma unroll
  for (int mi = 0; mi < 4; mi++){
    #pragma unroll
    for (int ni = 0; ni < 4; ni++){
      #pragma unroll
      for (int r = 0; r < 4; r++){
        int row = m0 + wm * 64 + mi * 16 + lq * 4 + r;
        int col = n0 + wn * 64 + ni * 16 + lrow;
        float v = acc[mi][ni][r];
        if (EPI == 1){
          if (rdt) v += ((const float*)Res)[(size_t)row * N + col];
          else     v += bf2f(((const u16*)Res)[(size_t)row * N + col]);
        }
        v = clamp_sig(v);
        if (odt) ((float*)C)[(size_t)row * N + col] = v;
        else     ((u16*)C)[(size_t)row * N + col] = f2bf(v);
      }
    }
  }
}

// ---------------- Dual-B MFMA GEMM (m97 structure) with SwiGLU epilogue ------
__global__ __launch_bounds__(256) void gemm_ffn_bt(const u16* __restrict__ A,
                                                   const u16* __restrict__ B1T,
                                                   const u16* __restrict__ B3T,
                                                   u16* __restrict__ G,
                                                   const u16* __restrict__ probe,
                                                   int M, int N, int K){
  int f = detect_fp32(probe);
  __shared__ u16 As[128 * 32];
  __shared__ u16 B1s[128 * 32];
  __shared__ u16 B3s[128 * 32];
  int t = threadIdx.x;
  int l = t & 63, w = t >> 6;
  int wm = w >> 1, wn = w & 1;
  int gx = gridDim.x, nwg = gx * gridDim.y;
  int orig = blockIdx.x + gx * blockIdx.y;
  int wg = (orig & 7) * (nwg >> 3) + (orig >> 3);
  int m0 = (wg / gx) * 128, n0 = (wg % gx) * 128;
  const int lrow = l & 15, lq = l >> 4;

  f32x4 acc1[4][4], acc3[4][4];
  #pragma unroll
  for (int i = 0; i < 4; i++)
    #pragma unroll
    for (int j = 0; j < 4; j++){
      acc1[i][j] = (f32x4){0.f, 0.f, 0.f, 0.f};
      acc3[i][j] = (f32x4){0.f, 0.f, 0.f, 0.f};
    }

  const u16* gA[2]; const u16* gB1[2]; const u16* gB3[2];
  #pragma unroll
  for (int i = 0; i < 2; i++){
    int c = i * 256 + t;
    gA[i]  = A   + (size_t)(m0 + (c >> 2)) * K + (c & 3) * 8;
    gB1[i] = B1T + (size_t)(n0 + (c >> 2)) * K + (c & 3) * 8;
    gB3[i] = B3T + (size_t)(n0 + (c >> 2)) * K + (c & 3) * 8;
  }
  u16* lA  = As  + (size_t)w * 512;
  u16* lB1 = B1s + (size_t)w * 512;
  u16* lB3 = B3s + (size_t)w * 512;

  for (int k0 = 0; k0 < K; k0 += 32){
    #pragma unroll
    for (int i = 0; i < 2; i++){
      gload16(gA[i]  + k0, lA  + i * 2048);
      gload16(gB1[i] + k0, lB1 + i * 2048);
      gload16(gB3[i] + k0, lB3 + i * 2048);
    }
    __syncthreads();
    bf16x8 aF[4], b1F[4], b3F[4];
    #pragma unroll
    for (int mi = 0; mi < 4; mi++)
      aF[mi] = *(const bf16x8*)(As + (wm * 64 + mi * 16 + lrow) * 32 + lq * 8);
    #pragma unroll
    for (int ni = 0; ni < 4; ni++){
      b1F[ni] = *(const bf16x8*)(B1s + (wn * 64 + ni * 16 + lrow) * 32 + lq * 8);
      b3F[ni] = *(const bf16x8*)(B3s + (wn * 64 + ni * 16 + lrow) * 32 + lq * 8);
    }
    #pragma unroll
    for (int mi = 0; mi < 4; mi++)
      #pragma unroll
      for (int ni = 0; ni < 4; ni++){
        acc1[mi][ni] = __builtin_amdgcn_mfma_f32_16x16x32_bf16(aF[mi], b1F[ni], acc1[mi][ni], 0, 0, 0);
        acc3[mi][ni] = __builtin_amdgcn_mfma_f32_16x16x32_bf16(aF[mi], b3F[ni], acc3[mi][ni], 0, 0, 0);
      }
    __syncthreads();
  }

  #pragma unroll
  for (int mi = 0; mi < 4; mi++){
    #pragma unroll
    for (int ni = 0; ni < 4; ni++){
      #pragma unroll
      for (int r = 0; r < 4; r++){
        int row = m0 + wm * 64 + mi * 16 + lq * 4 + r;
        int col = n0 + wn * 64 + ni * 16 + lrow;
        float g1 = acc1[mi][ni][r];
        float g3 = acc3[mi][ni][r];
        if (!f){ g1 = bf2f(f2bf(g1)); g3 = bf2f(f2bf(g3)); }
        float s  = g1 / (1.f + __expf(-g1));
        if (!f) s = bf2f(f2bf(s));
        float pr = s * g3;
        G[(size_t)row * N + col] = f2bf(clamp_sig(pr));
      }
    }
  }
}

// ---------------- MFMA flash attention ----------------
// Grid: 1024 blocks = B(2) * H(16) * (S/64=32 q-tiles), 256 threads (4 waves).
__global__ __launch_bounds__(256) void attn_k(const u16* __restrict__ Qg,
                                              const u16* __restrict__ Kg,
                                              const u16* __restrict__ Vg,
                                              u16* __restrict__ Og){
  __shared__ __align__(16) char KsB[64 * 256];     // 16 KB: K[64][128] bf16 (swizzled)
  __shared__ __align__(16) char VoB[8 * 2048];     // 16 KB: Voct[8][128][8] bf16 (swizzled)
  __shared__ __align__(16) u16  Ps[4][16 * 72];    // 9 KB:  per-wave P[16 q][64 k], stride 72

  const int t  = threadIdx.x;
  const int ln = t & 63;
  const int w  = t >> 6;
  const int q  = ln & 15;     // q-sub-row (fragment row/col index)
  const int g  = ln >> 4;     // lane group 0..3 (k-slice index)

  // XCD-aware swizzle: 1024 blocks, 8 XCDs -> 128-block contiguous chunks.
  int bid = (int)(blockIdx.x);
  int swz = (bid & 7) * 128 + (bid >> 3);
  int qt = swz & 31;
  int h  = (swz >> 5) & 15;
  int b  = swz >> 9;

  const size_t bbase = ((size_t)b * SS) * DD + (size_t)h * HDIM;
  const int q0 = qt * 64;
  const float scale = 0.08838834764831845f;  // 1/sqrt(128)

  u16* Psw = &Ps[w][0];

  // ---- Q fragments (pre-scaled bf16), held all kernel: Q[q0+w*16+q][d] ----
  bf16x8 qF[4];
  {
    const u16* qp = Qg + bbase + (size_t)(q0 + w * 16 + q) * DD + g * 8;
    #pragma unroll
    for (int ds = 0; ds < 4; ds++){
      uint4 raw = *(const uint4*)(qp + ds * 32);
      u16* rw = (u16*)&raw;
      u16 sc8[8];
      #pragma unroll
      for (int j = 0; j < 8; j++) sc8[j] = f2bf(bf2f(rw[j]) * scale);
      qF[ds] = *(bf16x8*)sc8;
    }
  }

  f32x4 ov[8];
  #pragma unroll
  for (int n = 0; n < 8; n++) ov[n] = (f32x4){0.f, 0.f, 0.f, 0.f};
  float m_state = -1e30f;
  float l_state = 0.f;

  for (int kt = 0; kt < 32; kt++){
    const int k0 = kt * 64;
    __syncthreads();   // previous iteration's LDS reads complete

    // ---- stage K tile: all 256 threads, b128 swizzled writes ----
    #pragma unroll
    for (int i = 0; i < 4; i++){
      int c = t + 256 * i;
      int row = c >> 4, cb = c & 15;
      uint4 val = *(const uint4*)(Kg + bbase + (size_t)(k0 + row) * DD + cb * 8);
      *(uint4*)(KsB + (((row << 8) | (cb << 4)) ^ ((row & 7) << 4))) = val;
    }
    // ---- stage V tile transposed: wave w handles oct planes 2w, 2w+1 ----
    #pragma unroll
    for (int oo = 0; oo < 2; oo++){
      int oct = w * 2 + oo;
      unsigned r[8];
      #pragma unroll
      for (int kk = 0; kk < 8; kk++)
        r[kk] = *(const unsigned*)(Vg + bbase + (size_t)(k0 + oct * 8 + kk) * DD + 2 * ln);
      uint4 lo, hi;
      lo.x = (r[0] & 0xffffu) | (r[1] << 16);
      lo.y = (r[2] & 0xffffu) | (r[3] << 16);
      lo.z = (r[4] & 0xffffu) | (r[5] << 16);
      lo.w = (r[6] & 0xffffu) | (r[7] << 16);
      hi.x = (r[0] >> 16) | (r[1] & 0xffff0000u);
      hi.y = (r[2] >> 16) | (r[3] & 0xffff0000u);
      hi.z = (r[4] >> 16) | (r[5] & 0xffff0000u);
      hi.w = (r[6] >> 16) | (r[7] & 0xffff0000u);
      int a0 = oct * 2048 + ((ln * 32) ^ ((ln & 7) << 4));   // d = 2*ln
      *(uint4*)(VoB + a0) = lo;                              // d even
      *(uint4*)(VoB + (a0 ^ 16)) = hi;                       // d = 2*ln+1
    }
    __syncthreads();   // staging visible

    // ---- QK^T (swapped): sc4[m] = S^T[k-subtile m][q] ----
    f32x4 sc4[4];
    #pragma unroll
    for (int m = 0; m < 4; m++) sc4[m] = (f32x4){0.f, 0.f, 0.f, 0.f};
    #pragma unroll
    for (int m = 0; m < 4; m++){
      int row = m * 16 + q;
      #pragma unroll
      for (int ds = 0; ds < 4; ds++){
        bf16x8 kf = *(const bf16x8*)(KsB +
            (((row << 8) | (ds << 6) | (g << 4)) ^ ((row & 7) << 4)));
        sc4[m] = __builtin_amdgcn_mfma_f32_16x16x32_bf16(kf, qF[ds], sc4[m], 0, 0, 0);
      }
    }

    // ---- online softmax (wave-parallel; rows are q = ln&15) ----
    float mt = -1e30f;
    #pragma unroll
    for (int m = 0; m < 4; m++){
      mt = fmaxf(mt, fmaxf(fmaxf(sc4[m][0], sc4[m][1]), fmaxf(sc4[m][2], sc4[m][3])));
    }
    mt = fmaxf(mt, __shfl_xor(mt, 16));
    mt = fmaxf(mt, __shfl_xor(mt, 32));
    float m_new = fmaxf(m_state, mt);
    float alpha = __expf(m_state - m_new);
    float rs = 0.f;
    #pragma unroll
    for (int m = 0; m < 4; m++){
      float p0 = __expf(sc4[m][0] - m_new);
      float p1 = __expf(sc4[m][1] - m_new);
      float p2 = __expf(sc4[m][2] - m_new);
      float p3 = __expf(sc4[m][3] - m_new);
      rs += (p0 + p1) + (p2 + p3);
      uint2 pw;
      pw.x = (unsigned)f2bf(p0) | ((unsigned)f2bf(p1) << 16);
      pw.y = (unsigned)f2bf(p2) | ((unsigned)f2bf(p3) << 16);
      *(uint2*)(Psw + q * 72 + m * 16 + g * 4) = pw;
    }
    rs += __shfl_xor(rs, 16);
    rs += __shfl_xor(rs, 32);
    l_state = l_state * alpha + rs;
    m_state = m_new;

    // ---- rescale O accumulators: component r is q-row g*4+r ----
    float a0 = __shfl(alpha, g * 4 + 0);
    float a1 = __shfl(alpha, g * 4 + 1);
    float a2 = __shfl(alpha, g * 4 + 2);
    float a3 = __shfl(alpha, g * 4 + 3);
    #pragma unroll
    for (int n = 0; n < 8; n++){
      ov[n][0] *= a0; ov[n][1] *= a1; ov[n][2] *= a2; ov[n][3] *= a3;
    }

    // ---- PV: O[q][d] += P[q][k] * V[k][d] (per-wave Ps, no barrier) ----
    bf16x8 pA0 = *(const bf16x8*)(Psw + q * 72 + g * 8);
    bf16x8 pA1 = *(const bf16x8*)(Psw + q * 72 + 32 + g * 8);
    #pragma unroll
    for (int n = 0; n < 8; n++){
      int d = n * 16 + q;
      int sw = ((d >> 1) & 7) << 4;
      bf16x8 v0 = *(const bf16x8*)(VoB + g * 2048 + ((d << 4) ^ sw));
      bf16x8 v1 = *(const bf16x8*)(VoB + (4 + g) * 2048 + ((d << 4) ^ sw));
      ov[n] = __builtin_amdgcn_mfma_f32_16x16x32_bf16(pA0, v0, ov[n], 0, 0, 0);
      ov[n] = __builtin_amdgcn_mfma_f32_16x16x32_bf16(pA1, v1, ov[n], 0, 0, 0);
    }
  }

  // ---- epilogue: O / l, write bf16 ----
  float li = 1.f / fmaxf(l_state, 1e-30f);   // valid for q = ln&15
  float l0 = __shfl(li, g * 4 + 0);
  float l1 = __shfl(li, g * 4 + 1);
  float l2 = __shfl(li, g * 4 + 2);
  float l3 = __shfl(li, g * 4 + 3);
  #pragma unroll
  for (int n = 0; n < 8; n++){
    int srow = q0 + w * 16 + g * 4;
    int d = n * 16 + q;
    u16* po = Og + bbase + (size_t)srow * DD + d;
    po[0]        = f2bf(clamp_sig(ov[n][0] * l0));
    po[DD]       = f2bf(clamp_sig(ov[n][1] * l1));
    po[2 * DD]   = f2bf(clamp_sig(ov[n][2] * l2));
    po[3 * DD]   = f2bf(clamp_sig(ov[n][3] * l3));
  }
}

extern "C" void kernel_launch(void* const* d_in, const int* in_sizes, int n_in,
                              void* d_out, int out_size, void* d_ws, size_t ws_size,
                              hipStream_t stream){
  (void)in_sizes; (void)n_in; (void)out_size; (void)ws_size;
  const void* x   = d_in[0];
  const void* fc  = d_in[1];
  const void* fs  = d_in[2];
  const void* wq  = d_in[3];
  const void* wk  = d_in[4];
  const void* wv  = d_in[5];
  const void* wo  = d_in[6];
  const void* w1  = d_in[7];
  const void* w2  = d_in[8];
  const void* w3  = d_in[9];
  const void* anw = d_in[10];
  const void* fnw = d_in[11];
  const u16* probe = (const u16*)wq;   // dtype probe tensor
  void* out = d_out;

  // ---- workspace layout (~153 MB, phased aliasing) ----
  char* ws = (char*)d_ws;
  size_t off = 0;
  auto alloc = [&](size_t bytes) -> u16* {
    u16* p = (u16*)(ws + off);
    off += (bytes + 255) & ~(size_t)255;
    return p;
  };
  const size_t SZ_MD = (size_t)MROWS * DD * 2;      // 16.78 MB
  const size_t SZ_DD = (size_t)DD * DD * 2;         //  8.39 MB (square weight T)
  const size_t SZ_HT = (size_t)HIDF * DD * 2;       // 23.07 MB (ffn weight T)

  u16* XN  = alloc(SZ_MD);
  u16* Qb  = alloc(SZ_MD);
  u16* Kb  = alloc(SZ_MD);
  u16* Vb  = alloc(SZ_MD);
  u16* Hb  = alloc(SZ_MD);
  u16* WA  = alloc(2 * SZ_HT);   // phase A: wqT/wkT/wvT; phase B: w1T/w3T
  u16* WB  = alloc(SZ_HT);       // phase A: woT;         phase B: w2T
  u16* AO  = XN;                 // alias: XN dead when attention output written
  u16* G   = Qb;                 // alias: Q/K/V dead in FFN phase (46.1 <= 50.3 MB)
  u16* wqT = WA;
  u16* wkT = WA + (size_t)DD * DD;
  u16* wvT = WA + 2 * (size_t)DD * DD;
  u16* woT = WB;
  u16* w1T = WA;                 // overwrites wq/wk/wvT (dead after QKV gemms)
  u16* w3T = WA + (size_t)HIDF * DD;
  u16* w2T = WB;                 // overwrites woT (dead after wo gemm)

  // --- attention sub-block ---
  transpose_k<<<dim3(32, 32), 256, 0, stream>>>(wq, wqT, DD, DD, probe);
  transpose_k<<<dim3(32, 32), 256, 0, stream>>>(wk, wkT, DD, DD, probe);
  transpose_k<<<dim3(32, 32), 256, 0, stream>>>(wv, wvT, DD, DD, probe);
  transpose_k<<<dim3(32, 32), 256, 0, stream>>>(wo, woT, DD, DD, probe);
  rmsnorm_k<<<MROWS, 256, 0, stream>>>(x, anw, XN, probe, 1);
  gemm_bt<0><<<dim3(16, 32), 256, 0, stream>>>(XN, wqT, Qb, nullptr, probe, MROWS, DD, DD, 0, 0);
  gemm_bt<0><<<dim3(16, 32), 256, 0, stream>>>(XN, wkT, Kb, nullptr, probe, MROWS, DD, DD, 0, 0);
  gemm_bt<0><<<dim3(16, 32), 256, 0, stream>>>(XN, wvT, Vb, nullptr, probe, MROWS, DD, DD, 0, 0);
  rope_k<<<16384, 256, 0, stream>>>(Qb, fc, fs, probe);
  rope_k<<<16384, 256, 0, stream>>>(Kb, fc, fs, probe);
  attn_k<<<1024, 256, 0, stream>>>(Qb, Kb, Vb, AO);
  gemm_bt<1><<<dim3(16, 32), 256, 0, stream>>>(AO, woT, Hb, x, probe, MROWS, DD, DD, 1, 0);

  // --- SwiGLU FFN sub-block ---
  transpose_k<<<dim3(88, 32), 256, 0, stream>>>(w1, w1T, DD, HIDF, probe);
  transpose_k<<<dim3(88, 32), 256, 0, stream>>>(w3, w3T, DD, HIDF, probe);
  transpose_k<<<dim3(32, 88), 256, 0, stream>>>(w2, w2T, HIDF, DD, probe);
  rmsnorm_k<<<MROWS, 256, 0, stream>>>(Hb, fnw, XN, probe, 0);
  gemm_ffn_bt<<<dim3(44, 32), 256, 0, stream>>>(XN, w1T, w3T, G, probe, MROWS, HIDF, DD);
  gemm_bt<1><<<dim3(16, 32), 256, 0, stream>>>(G, w2T, out, Hb, probe, MROWS, DD, HIDF, 0, 1);
}

// Round 3
// 1229.206 us; speedup vs baseline: 4.2594x; 1.2047x over previous
//
#include <hip/hip_runtime.h>
#include <hip/hip_bf16.h>

typedef unsigned short u16;
typedef short bf16x8 __attribute__((ext_vector_type(8)));
typedef float f32x4 __attribute__((ext_vector_type(4)));

#define BB 2
#define SS 2048
#define DD 2048
#define HH 16
#define HDIM 128
#define HIDF 5632
#define MROWS (BB*SS)   // 4096

__device__ __forceinline__ float bf2f(u16 x){
  union { unsigned u; float f; } c; c.u = ((unsigned)x) << 16; return c.f;
}
__device__ __forceinline__ u16 f2bf(float f){
  union { float f; unsigned u; } c; c.f = f;
  unsigned u = c.u;
  u += 0x7FFFu + ((u >> 16) & 1u);   // RNE
  return (u16)(u >> 16);
}
__device__ __forceinline__ float clamp_sig(float v){
  // NaN -> +8192 (diagnostic signal); legit values never reach +-8192
  return fmaxf(fminf(v, 8192.f), -8192.f);
}

// async global->LDS, 16B per lane. lds base must be wave-uniform.
__device__ __forceinline__ void gload16(const void* g, void* l){
  __builtin_amdgcn_global_load_lds((const __attribute__((address_space(1))) void*)g,
                                   (__attribute__((address_space(3))) void*)l,
                                   16, 0, 0);
}

// Per-block input-dtype detection: scan u16 of a weight tensor.
// bf16 weights (sigma=0.02): exponent field always < 0x90.
// fp32 data read as u16: even halves are mantissa garbage, ~44% >= 0x90.
__device__ int detect_fp32(const u16* __restrict__ probe){
  __shared__ int sflag;
  if (threadIdx.x == 0) sflag = 0;
  __syncthreads();
  int bad = 0;
  #pragma unroll
  for (int i = 0; i < 8; i++){
    u16 v = probe[threadIdx.x * 8 + i];
    int e = (v >> 7) & 0xFF;
    bad += (e >= 0x90);
  }
  if (bad) atomicAdd(&sflag, bad);
  __syncthreads();
  return sflag > 16;
}

// ---------------- weight transpose+cast: W[K][N] (f?fp32:bf16) -> WT[N][K] bf16 ----
// grid: (N/64, K/64), 256 threads. 64x64 tile via LDS.
__global__ __launch_bounds__(256) void transpose_k(const void* __restrict__ W,
                                                   u16* __restrict__ WT,
                                                   int K, int N,
                                                   const u16* __restrict__ probe){
  int f = detect_fp32(probe);
  __shared__ u16 T[64][72];   // +8 pad; rows 144B (16B-aligned)
  int n0 = blockIdx.x * 64, k0 = blockIdx.y * 64;
  int t = threadIdx.x;
  int row = t >> 3, c8 = (t & 7) * 8;
  #pragma unroll
  for (int i = 0; i < 2; i++){
    int r = row + 32 * i;
    if (!f){
      uint4 v = *(const uint4*)((const u16*)W + (size_t)(k0 + r) * N + n0 + c8);
      *(uint4*)&T[r][c8] = v;
    } else {
      const float* gp = (const float*)W + (size_t)(k0 + r) * N + n0 + c8;
      float4 a = *(const float4*)gp;
      float4 b = *(const float4*)(gp + 4);
      u16 tmp[8] = {f2bf(a.x), f2bf(a.y), f2bf(a.z), f2bf(a.w),
                    f2bf(b.x), f2bf(b.y), f2bf(b.z), f2bf(b.w)};
      *(uint4*)&T[r][c8] = *(uint4*)tmp;
    }
  }
  __syncthreads();
  #pragma unroll
  for (int i = 0; i < 2; i++){
    int r = row + 32 * i;      // output n-offset
    u16 o[8];
    #pragma unroll
    for (int j = 0; j < 8; j++) o[j] = T[c8 + j][r];
    *(uint4*)(WT + (size_t)(n0 + r) * K + k0 + c8) = *(uint4*)o;
  }
}

// ---------------- RMSNorm: row of 2048 -> bf16 out ----------------
__global__ __launch_bounds__(256) void rmsnorm_k(const void* __restrict__ src,
                                                 const void* __restrict__ w,
                                                 u16* __restrict__ y,
                                                 const u16* __restrict__ probe,
                                                 int src_probe){
  int f = detect_fp32(probe);
  int sdt = src_probe ? f : 0;
  int row = blockIdx.x, t = threadIdx.x;
  float v[8];
  if (sdt){
    const float* xr = (const float*)src + (size_t)row * DD + t * 8;
    float4 p0 = *(const float4*)xr;
    float4 p1 = *(const float4*)(xr + 4);
    v[0] = p0.x; v[1] = p0.y; v[2] = p0.z; v[3] = p0.w;
    v[4] = p1.x; v[5] = p1.y; v[6] = p1.z; v[7] = p1.w;
  } else {
    const u16* xr = (const u16*)src + (size_t)row * DD + t * 8;
    uint4 pk = *(const uint4*)xr;
    u16* pv = (u16*)&pk;
    #pragma unroll
    for (int i = 0; i < 8; i++) v[i] = bf2f(pv[i]);
  }
  float ss = 0.f;
  #pragma unroll
  for (int i = 0; i < 8; i++) ss += v[i] * v[i];
  #pragma unroll
  for (int off = 32; off > 0; off >>= 1) ss += __shfl_down(ss, off, 64);
  __shared__ float red[4];
  if ((t & 63) == 0) red[t >> 6] = ss;
  __syncthreads();
  if (t == 0){
    float s = red[0] + red[1] + red[2] + red[3];
    red[0] = rsqrtf(s / (float)DD + 1e-5f);
  }
  __syncthreads();
  float r = red[0];
  float wf[8];
  if (f){
    const float* wp = (const float*)w + t * 8;
    float4 a = *(const float4*)wp;
    float4 b = *(const float4*)(wp + 4);
    wf[0] = a.x; wf[1] = a.y; wf[2] = a.z; wf[3] = a.w;
    wf[4] = b.x; wf[5] = b.y; wf[6] = b.z; wf[7] = b.w;
  } else {
    const u16* wp = (const u16*)w + t * 8;
    uint4 wk = *(const uint4*)wp;
    u16* pw = (u16*)&wk;
    #pragma unroll
    for (int i = 0; i < 8; i++) wf[i] = bf2f(pw[i]);
  }
  u16 ob[8];
  #pragma unroll
  for (int i = 0; i < 8; i++){
    float yn = v[i] * r;
    if (!f) yn = bf2f(f2bf(yn));   // bf16 world: ref casts to bf16 before *w
    ob[i] = f2bf(yn * wf[i]);
  }
  *(uint4*)(y + (size_t)row * DD + t * 8) = *(uint4*)ob;
}

// ---------------- RoPE in-place on [B,S,H,HD] (ws, bf16) ----------------
__global__ __launch_bounds__(256) void rope_k(u16* __restrict__ x,
                                              const void* __restrict__ cosb,
                                              const void* __restrict__ sinb,
                                              const u16* __restrict__ probe){
  int f = detect_fp32(probe);
  size_t i = (size_t)blockIdx.x * 256 + threadIdx.x;  // pair index
  int p = (int)(i & 63);
  int s = (int)((i >> 10) & (SS - 1));
  u16* px = x + i * 2;
  float a = bf2f(px[0]), b = bf2f(px[1]);
  float c, sn;
  if (f){
    c  = ((const float*)cosb)[s * 64 + p];
    sn = ((const float*)sinb)[s * 64 + p];
  } else {
    c  = bf2f(((const u16*)cosb)[s * 64 + p]);
    sn = bf2f(((const u16*)sinb)[s * 64 + p]);
  }
  px[0] = f2bf(a * c - b * sn);
  px[1] = f2bf(a * sn + b * c);
}

// ---------------- MFMA GEMM (m97 structure): C[M,N] = A[M,K] @ BT[N,K]^T (+Res) ----
// A, BT: bf16, k-contiguous. global_load_lds width-16 staging, linear LDS,
// 128x128 tile, BK=32, XCD-aware block swizzle (grid % 8 == 0).
template<int EPI>
__global__ __launch_bounds__(256) void gemm_bt(const u16* __restrict__ A,
                                               const u16* __restrict__ BT,
                                               void* __restrict__ C,
                                               const void* __restrict__ Res,
                                               const u16* __restrict__ probe,
                                               int M, int N, int K,
                                               int res_probe, int out_probe){
  int f = detect_fp32(probe);
  __shared__ u16 As[128 * 32];
  __shared__ u16 Bs[128 * 32];
  int t = threadIdx.x;
  int l = t & 63, w = t >> 6;
  int wm = w >> 1, wn = w & 1;
  int gx = gridDim.x, nwg = gx * gridDim.y;
  int orig = blockIdx.x + gx * blockIdx.y;
  int wg = (orig & 7) * (nwg >> 3) + (orig >> 3);
  int m0 = (wg / gx) * 128, n0 = (wg % gx) * 128;
  const int lrow = l & 15, lq = l >> 4;

  f32x4 acc[4][4];
  #pragma unroll
  for (int i = 0; i < 4; i++)
    #pragma unroll
    for (int j = 0; j < 4; j++) acc[i][j] = (f32x4){0.f, 0.f, 0.f, 0.f};

  const u16* gA[2]; const u16* gB[2];
  #pragma unroll
  for (int i = 0; i < 2; i++){
    int c = i * 256 + t;
    gA[i] = A  + (size_t)(m0 + (c >> 2)) * K + (c & 3) * 8;
    gB[i] = BT + (size_t)(n0 + (c >> 2)) * K + (c & 3) * 8;
  }
  u16* lA = As + (size_t)w * 512;   // wave-uniform LDS bases (u16 units)
  u16* lB = Bs + (size_t)w * 512;

  for (int k0 = 0; k0 < K; k0 += 32){
    #pragma unroll
    for (int i = 0; i < 2; i++){
      gload16(gA[i] + k0, lA + i * 2048);
      gload16(gB[i] + k0, lB + i * 2048);
    }
    __syncthreads();
    bf16x8 aF[4], bF[4];
    #pragma unroll
    for (int mi = 0; mi < 4; mi++)
      aF[mi] = *(const bf16x8*)(As + (wm * 64 + mi * 16 + lrow) * 32 + lq * 8);
    #pragma unroll
    for (int ni = 0; ni < 4; ni++)
      bF[ni] = *(const bf16x8*)(Bs + (wn * 64 + ni * 16 + lrow) * 32 + lq * 8);
    #pragma unroll
    for (int mi = 0; mi < 4; mi++)
      #pragma unroll
      for (int ni = 0; ni < 4; ni++)
        acc[mi][ni] = __builtin_amdgcn_mfma_f32_16x16x32_bf16(aF[mi], bF[ni], acc[mi][ni], 0, 0, 0);
    __syncthreads();
  }

  int rdt = res_probe ? f : 0;
  int odt = out_probe ? f : 0;
  #pragma unroll
  for (int mi = 0; mi < 4; mi++){
    #pragma unroll
    for (int ni = 0; ni < 4; ni++){
      #pragma unroll
      for (int r = 0; r < 4; r++){
        int row = m0 + wm * 64 + mi * 16 + lq * 4 + r;
        int col = n0 + wn * 64 + ni * 16 + lrow;
        float v = acc[mi][ni][r];
        if (EPI == 1){
          if (rdt) v += ((const float*)Res)[(size_t)row * N + col];
          else     v += bf2f(((const u16*)Res)[(size_t)row * N + col]);
        }
        v = clamp_sig(v);
        if (odt) ((float*)C)[(size_t)row * N + col] = v;
        else     ((u16*)C)[(size_t)row * N + col] = f2bf(v);
      }
    }
  }
}

// ---------------- Dual-B MFMA GEMM with SwiGLU epilogue (8-wave) -------------
// 512 threads, 128x128 tile, wave-tile 32(M)x64(N), dual acc = 2x4 frags/set
// -> 64 acc regs/wave (~184 total, 2 waves/SIMD; the 4-wave version was 264
// regs -> 1 wave/SIMD, zero latency hiding).
// Column-major-within-XCD-chunk ordering: chunk = 11 n-cols x 32 m-tiles, so
// the 1MB B1+B3 panel of the active n-col stays L2-resident; A streams from L3.
__global__ __launch_bounds__(512) void gemm_ffn_bt(const u16* __restrict__ A,
                                                   const u16* __restrict__ B1T,
                                                   const u16* __restrict__ B3T,
                                                   u16* __restrict__ G,
                                                   const u16* __restrict__ probe,
                                                   int M, int N, int K){
  int f = detect_fp32(probe);
  __shared__ u16 As[128 * 32];
  __shared__ u16 B1s[128 * 32];
  __shared__ u16 B3s[128 * 32];
  int t = threadIdx.x;
  int l = t & 63, w = t >> 6;          // 8 waves
  int wm = w >> 1, wn = w & 1;         // 4 m-quarters x 2 n-halves
  int gx = gridDim.x, gy = gridDim.y, nwg = gx * gy;
  int orig = blockIdx.x + gx * blockIdx.y;
  int wg = (orig & 7) * (nwg >> 3) + (orig >> 3);
  int m0 = (wg % gy) * 128, n0 = (wg / gy) * 128;   // col-major within chunk
  const int lrow = l & 15, lq = l >> 4;

  f32x4 acc1[2][4], acc3[2][4];
  #pragma unroll
  for (int i = 0; i < 2; i++)
    #pragma unroll
    for (int j = 0; j < 4; j++){
      acc1[i][j] = (f32x4){0.f, 0.f, 0.f, 0.f};
      acc3[i][j] = (f32x4){0.f, 0.f, 0.f, 0.f};
    }

  // 512 threads x 16B = one full 128x32 tile per issue
  const u16* gA  = A   + (size_t)((t >> 2)) * K + (t & 3) * 8 + (size_t)m0 * K;
  const u16* gB1 = B1T + (size_t)((t >> 2)) * K + (t & 3) * 8 + (size_t)n0 * K;
  const u16* gB3 = B3T + (size_t)((t >> 2)) * K + (t & 3) * 8 + (size_t)n0 * K;
  u16* lA  = As  + (size_t)w * 512;   // wave-uniform LDS bases (u16 units)
  u16* lB1 = B1s + (size_t)w * 512;
  u16* lB3 = B3s + (size_t)w * 512;

  for (int k0 = 0; k0 < K; k0 += 32){
    gload16(gA  + k0, lA);
    gload16(gB1 + k0, lB1);
    gload16(gB3 + k0, lB3);
    __syncthreads();
    bf16x8 aF[2], b1F[4], b3F[4];
    #pragma unroll
    for (int mi = 0; mi < 2; mi++)
      aF[mi] = *(const bf16x8*)(As + (wm * 32 + mi * 16 + lrow) * 32 + lq * 8);
    #pragma unroll
    for (int ni = 0; ni < 4; ni++){
      b1F[ni] = *(const bf16x8*)(B1s + (wn * 64 + ni * 16 + lrow) * 32 + lq * 8);
      b3F[ni] = *(const bf16x8*)(B3s + (wn * 64 + ni * 16 + lrow) * 32 + lq * 8);
    }
    #pragma unroll
    for (int mi = 0; mi < 2; mi++)
      #pragma unroll
      for (int ni = 0; ni < 4; ni++){
        acc1[mi][ni] = __builtin_amdgcn_mfma_f32_16x16x32_bf16(aF[mi], b1F[ni], acc1[mi][ni], 0, 0, 0);
        acc3[mi][ni] = __builtin_amdgcn_mfma_f32_16x16x32_bf16(aF[mi], b3F[ni], acc3[mi][ni], 0, 0, 0);
      }
    __syncthreads();
  }

  #pragma unroll
  for (int mi = 0; mi < 2; mi++){
    #pragma unroll
    for (int ni = 0; ni < 4; ni++){
      #pragma unroll
      for (int r = 0; r < 4; r++){
        int row = m0 + wm * 32 + mi * 16 + lq * 4 + r;
        int col = n0 + wn * 64 + ni * 16 + lrow;
        float g1 = acc1[mi][ni][r];
        float g3 = acc3[mi][ni][r];
        if (!f){ g1 = bf2f(f2bf(g1)); g3 = bf2f(f2bf(g3)); }
        float s  = g1 / (1.f + __expf(-g1));
        if (!f) s = bf2f(f2bf(s));
        float pr = s * g3;
        G[(size_t)row * N + col] = f2bf(clamp_sig(pr));
      }
    }
  }
}

// ---------------- MFMA flash attention ----------------
// Grid: 1024 blocks = B(2) * H(16) * (S/64=32 q-tiles), 256 threads (4 waves).
__global__ __launch_bounds__(256) void attn_k(const u16* __restrict__ Qg,
                                              const u16* __restrict__ Kg,
                                              const u16* __restrict__ Vg,
                                              u16* __restrict__ Og){
  __shared__ __align__(16) char KsB[64 * 256];     // 16 KB: K[64][128] bf16 (swizzled)
  __shared__ __align__(16) char VoB[8 * 2048];     // 16 KB: Voct[8][128][8] bf16 (swizzled)
  __shared__ __align__(16) u16  Ps[4][16 * 72];    // 9 KB:  per-wave P[16 q][64 k], stride 72

  const int t  = threadIdx.x;
  const int ln = t & 63;
  const int w  = t >> 6;
  const int q  = ln & 15;     // q-sub-row (fragment row/col index)
  const int g  = ln >> 4;     // lane group 0..3 (k-slice index)

  // XCD-aware swizzle: 1024 blocks, 8 XCDs -> 128-block contiguous chunks.
  int bid = (int)(blockIdx.x);
  int swz = (bid & 7) * 128 + (bid >> 3);
  int qt = swz & 31;
  int h  = (swz >> 5) & 15;
  int b  = swz >> 9;

  const size_t bbase = ((size_t)b * SS) * DD + (size_t)h * HDIM;
  const int q0 = qt * 64;
  const float scale = 0.08838834764831845f;  // 1/sqrt(128)

  u16* Psw = &Ps[w][0];

  // ---- Q fragments (pre-scaled bf16), held all kernel: Q[q0+w*16+q][d] ----
  bf16x8 qF[4];
  {
    const u16* qp = Qg + bbase + (size_t)(q0 + w * 16 + q) * DD + g * 8;
    #pragma unroll
    for (int ds = 0; ds < 4; ds++){
      uint4 raw = *(const uint4*)(qp + ds * 32);
      u16* rw = (u16*)&raw;
      u16 sc8[8];
      #pragma unroll
      for (int j = 0; j < 8; j++) sc8[j] = f2bf(bf2f(rw[j]) * scale);
      qF[ds] = *(bf16x8*)sc8;
    }
  }

  f32x4 ov[8];
  #pragma unroll
  for (int n = 0; n < 8; n++) ov[n] = (f32x4){0.f, 0.f, 0.f, 0.f};
  float m_state = -1e30f;
  float l_state = 0.f;

  for (int kt = 0; kt < 32; kt++){
    const int k0 = kt * 64;
    __syncthreads();   // previous iteration's LDS reads complete

    // ---- stage K tile: all 256 threads, b128 swizzled writes ----
    #pragma unroll
    for (int i = 0; i < 4; i++){
      int c = t + 256 * i;
      int row = c >> 4, cb = c & 15;
      uint4 val = *(const uint4*)(Kg + bbase + (size_t)(k0 + row) * DD + cb * 8);
      *(uint4*)(KsB + (((row << 8) | (cb << 4)) ^ ((row & 7) << 4))) = val;
    }
    // ---- stage V tile transposed: wave w handles oct planes 2w, 2w+1 ----
    #pragma unroll
    for (int oo = 0; oo < 2; oo++){
      int oct = w * 2 + oo;
      unsigned r[8];
      #pragma unroll
      for (int kk = 0; kk < 8; kk++)
        r[kk] = *(const unsigned*)(Vg + bbase + (size_t)(k0 + oct * 8 + kk) * DD + 2 * ln);
      uint4 lo, hi;
      lo.x = (r[0] & 0xffffu) | (r[1] << 16);
      lo.y = (r[2] & 0xffffu) | (r[3] << 16);
      lo.z = (r[4] & 0xffffu) | (r[5] << 16);
      lo.w = (r[6] & 0xffffu) | (r[7] << 16);
      hi.x = (r[0] >> 16) | (r[1] & 0xffff0000u);
      hi.y = (r[2] >> 16) | (r[3] & 0xffff0000u);
      hi.z = (r[4] >> 16) | (r[5] & 0xffff0000u);
      hi.w = (r[6] >> 16) | (r[7] & 0xffff0000u);
      int a0 = oct * 2048 + ((ln * 32) ^ ((ln & 7) << 4));   // d = 2*ln
      *(uint4*)(VoB + a0) = lo;                              // d even
      *(uint4*)(VoB + (a0 ^ 16)) = hi;                       // d = 2*ln+1
    }
    __syncthreads();   // staging visible

    // ---- QK^T (swapped): sc4[m] = S^T[k-subtile m][q] ----
    f32x4 sc4[4];
    #pragma unroll
    for (int m = 0; m < 4; m++) sc4[m] = (f32x4){0.f, 0.f, 0.f, 0.f};
    #pragma unroll
    for (int m = 0; m < 4; m++){
      int row = m * 16 + q;
      #pragma unroll
      for (int ds = 0; ds < 4; ds++){
        bf16x8 kf = *(const bf16x8*)(KsB +
            (((row << 8) | (ds << 6) | (g << 4)) ^ ((row & 7) << 4)));
        sc4[m] = __builtin_amdgcn_mfma_f32_16x16x32_bf16(kf, qF[ds], sc4[m], 0, 0, 0);
      }
    }

    // ---- online softmax (wave-parallel; rows are q = ln&15) ----
    float mt = -1e30f;
    #pragma unroll
    for (int m = 0; m < 4; m++){
      mt = fmaxf(mt, fmaxf(fmaxf(sc4[m][0], sc4[m][1]), fmaxf(sc4[m][2], sc4[m][3])));
    }
    mt = fmaxf(mt, __shfl_xor(mt, 16));
    mt = fmaxf(mt, __shfl_xor(mt, 32));
    float m_new = fmaxf(m_state, mt);
    float alpha = __expf(m_state - m_new);
    float rs = 0.f;
    #pragma unroll
    for (int m = 0; m < 4; m++){
      float p0 = __expf(sc4[m][0] - m_new);
      float p1 = __expf(sc4[m][1] - m_new);
      float p2 = __expf(sc4[m][2] - m_new);
      float p3 = __expf(sc4[m][3] - m_new);
      rs += (p0 + p1) + (p2 + p3);
      uint2 pw;
      pw.x = (unsigned)f2bf(p0) | ((unsigned)f2bf(p1) << 16);
      pw.y = (unsigned)f2bf(p2) | ((unsigned)f2bf(p3) << 16);
      *(uint2*)(Psw + q * 72 + m * 16 + g * 4) = pw;
    }
    rs += __shfl_xor(rs, 16);
    rs += __shfl_xor(rs, 32);
    l_state = l_state * alpha + rs;
    m_state = m_new;

    // ---- rescale O accumulators: component r is q-row g*4+r ----
    float a0 = __shfl(alpha, g * 4 + 0);
    float a1 = __shfl(alpha, g * 4 + 1);
    float a2 = __shfl(alpha, g * 4 + 2);
    float a3 = __shfl(alpha, g * 4 + 3);
    #pragma unroll
    for (int n = 0; n < 8; n++){
      ov[n][0] *= a0; ov[n][1] *= a1; ov[n][2] *= a2; ov[n][3] *= a3;
    }

    // ---- PV: O[q][d] += P[q][k] * V[k][d] (per-wave Ps, no barrier) ----
    bf16x8 pA0 = *(const bf16x8*)(Psw + q * 72 + g * 8);
    bf16x8 pA1 = *(const bf16x8*)(Psw + q * 72 + 32 + g * 8);
    #pragma unroll
    for (int n = 0; n < 8; n++){
      int d = n * 16 + q;
      int sw = ((d >> 1) & 7) << 4;
      bf16x8 v0 = *(const bf16x8*)(VoB + g * 2048 + ((d << 4) ^ sw));
      bf16x8 v1 = *(const bf16x8*)(VoB + (4 + g) * 2048 + ((d << 4) ^ sw));
      ov[n] = __builtin_amdgcn_mfma_f32_16x16x32_bf16(pA0, v0, ov[n], 0, 0, 0);
      ov[n] = __builtin_amdgcn_mfma_f32_16x16x32_bf16(pA1, v1, ov[n], 0, 0, 0);
    }
  }

  // ---- epilogue: O / l, write bf16 ----
  float li = 1.f / fmaxf(l_state, 1e-30f);   // valid for q = ln&15
  float l0 = __shfl(li, g * 4 + 0);
  float l1 = __shfl(li, g * 4 + 1);
  float l2 = __shfl(li, g * 4 + 2);
  float l3 = __shfl(li, g * 4 + 3);
  #pragma unroll
  for (int n = 0; n < 8; n++){
    int srow = q0 + w * 16 + g * 4;
    int d = n * 16 + q;
    u16* po = Og + bbase + (size_t)srow * DD + d;
    po[0]        = f2bf(clamp_sig(ov[n][0] * l0));
    po[DD]       = f2bf(clamp_sig(ov[n][1] * l1));
    po[2 * DD]   = f2bf(clamp_sig(ov[n][2] * l2));
    po[3 * DD]   = f2bf(clamp_sig(ov[n][3] * l3));
  }
}

extern "C" void kernel_launch(void* const* d_in, const int* in_sizes, int n_in,
                              void* d_out, int out_size, void* d_ws, size_t ws_size,
                              hipStream_t stream){
  (void)in_sizes; (void)n_in; (void)out_size; (void)ws_size;
  const void* x   = d_in[0];
  const void* fc  = d_in[1];
  const void* fs  = d_in[2];
  const void* wq  = d_in[3];
  const void* wk  = d_in[4];
  const void* wv  = d_in[5];
  const void* wo  = d_in[6];
  const void* w1  = d_in[7];
  const void* w2  = d_in[8];
  const void* w3  = d_in[9];
  const void* anw = d_in[10];
  const void* fnw = d_in[11];
  const u16* probe = (const u16*)wq;   // dtype probe tensor
  void* out = d_out;

  // ---- workspace layout (~153 MB, phased aliasing) ----
  char* ws = (char*)d_ws;
  size_t off = 0;
  auto alloc = [&](size_t bytes) -> u16* {
    u16* p = (u16*)(ws + off);
    off += (bytes + 255) & ~(size_t)255;
    return p;
  };
  const size_t SZ_MD = (size_t)MROWS * DD * 2;      // 16.78 MB
  const size_t SZ_DD = (size_t)DD * DD * 2;         //  8.39 MB (square weight T)
  const size_t SZ_HT = (size_t)HIDF * DD * 2;       // 23.07 MB (ffn weight T)

  u16* XN  = alloc(SZ_MD);
  u16* Qb  = alloc(SZ_MD);
  u16* Kb  = alloc(SZ_MD);
  u16* Vb  = alloc(SZ_MD);
  u16* Hb  = alloc(SZ_MD);
  u16* WA  = alloc(2 * SZ_HT);   // phase A: wqT/wkT/wvT; phase B: w1T/w3T
  u16* WB  = alloc(SZ_HT);       // phase A: woT;         phase B: w2T
  u16* AO  = XN;                 // alias: XN dead when attention output written
  u16* G   = Qb;                 // alias: Q/K/V dead in FFN phase (46.1 <= 50.3 MB)
  u16* wqT = WA;
  u16* wkT = WA + (size_t)DD * DD;
  u16* wvT = WA + 2 * (size_t)DD * DD;
  u16* woT = WB;
  u16* w1T = WA;                 // overwrites wq/wk/wvT (dead after QKV gemms)
  u16* w3T = WA + (size_t)HIDF * DD;
  u16* w2T = WB;                 // overwrites woT (dead after wo gemm)

  // --- attention sub-block ---
  transpose_k<<<dim3(32, 32), 256, 0, stream>>>(wq, wqT, DD, DD, probe);
  transpose_k<<<dim3(32, 32), 256, 0, stream>>>(wk, wkT, DD, DD, probe);
  transpose_k<<<dim3(32, 32), 256, 0, stream>>>(wv, wvT, DD, DD, probe);
  transpose_k<<<dim3(32, 32), 256, 0, stream>>>(wo, woT, DD, DD, probe);
  rmsnorm_k<<<MROWS, 256, 0, stream>>>(x, anw, XN, probe, 1);
  gemm_bt<0><<<dim3(16, 32), 256, 0, stream>>>(XN, wqT, Qb, nullptr, probe, MROWS, DD, DD, 0, 0);
  gemm_bt<0><<<dim3(16, 32), 256, 0, stream>>>(XN, wkT, Kb, nullptr, probe, MROWS, DD, DD, 0, 0);
  gemm_bt<0><<<dim3(16, 32), 256, 0, stream>>>(XN, wvT, Vb, nullptr, probe, MROWS, DD, DD, 0, 0);
  rope_k<<<16384, 256, 0, stream>>>(Qb, fc, fs, probe);
  rope_k<<<16384, 256, 0, stream>>>(Kb, fc, fs, probe);
  attn_k<<<1024, 256, 0, stream>>>(Qb, Kb, Vb, AO);
  gemm_bt<1><<<dim3(16, 32), 256, 0, stream>>>(AO, woT, Hb, x, probe, MROWS, DD, DD, 1, 0);

  // --- SwiGLU FFN sub-block ---
  transpose_k<<<dim3(88, 32), 256, 0, stream>>>(w1, w1T, DD, HIDF, probe);
  transpose_k<<<dim3(88, 32), 256, 0, stream>>>(w3, w3T, DD, HIDF, probe);
  transpose_k<<<dim3(32, 88), 256, 0, stream>>>(w2, w2T, HIDF, DD, probe);
  rmsnorm_k<<<MROWS, 256, 0, stream>>>(Hb, fnw, XN, probe, 0);
  gemm_ffn_bt<<<dim3(44, 32), 512, 0, stream>>>(XN, w1T, w3T, G, probe, MROWS, HIDF, DD);
  gemm_bt<1><<<dim3(16, 32), 256, 0, stream>>>(G, w2T, out, Hb, probe, MROWS, DD, HIDF, 0, 1);
}